// Round 7
// baseline (2730.723 us; speedup 1.0000x reference)
//
#include <hip/hip_runtime.h>
#include <math.h>

// ---------------- problem constants ----------------
#define NLAY 120         // LSTM layers
#define TT   1016        // LSTM time steps (1024 - 4 - 4)
#define NSEG 24          // segments of 5 layers; 24*5 = 120
#define HOPS 23          // inter-segment L3 hops per chain
#define G8   8           // hand-off batch (time steps)
#define NBAT 127         // batches of 8: 127*8 = 1016 exactly
#define RB   16          // ring depth in batches (power of 2)
#define BIGF (1 << 20)

typedef float v2f __attribute__((ext_vector_type(2)));

__device__ __forceinline__ float fast_rcp(float x) { return __builtin_amdgcn_rcpf(x); }
__device__ __forceinline__ float fast_sig(float x) { return fast_rcp(1.f + __expf(-x)); }
__device__ __forceinline__ float fast_tanh(float x) { return 1.f - 2.f * fast_rcp(1.f + __expf(2.f * x)); }

// agent-scope relaxed poll; s_sleep on miss; watchdog fails loud, never hangs
__device__ __forceinline__ int poll_ge_ag(const int* p, int tgt, int cur) {
  long g = 0;
  while (cur < tgt) {
    cur = __hip_atomic_load(p, __ATOMIC_RELAXED, __HIP_MEMORY_SCOPE_AGENT);
    if (cur >= tgt) break;
    __builtin_amdgcn_s_sleep(1);
    if (++g > 400000L) break;
  }
  return cur;
}

// ---------------- conv1d(6->6,K=5,valid) + bias, accumulate BN stats ----------------
__global__ void k_conv(const float* __restrict__ xin, const float* __restrict__ cw,
                       const float* __restrict__ cb, const float* __restrict__ aff,
                       float* __restrict__ yout, float* __restrict__ stat,
                       int Tin, int Tout, int use_aff)
{
  const int bx = blockIdx.x;            // 0..383 : b*6+co
  const int b = bx / 6, co = bx - b * 6;
  const int tid = threadIdx.x;          // 256
  __shared__ float wsh[30];
  __shared__ float ssh[6], shsh[6];
  if (tid < 30) wsh[tid] = cw[co * 30 + tid];
  if (tid < 6) {
    ssh[tid]  = use_aff ? aff[tid] : 1.f;
    shsh[tid] = use_aff ? aff[6 + tid] : 0.f;
  }
  __syncthreads();
  const float bias = cb[co];
  float lsum = 0.f, lsq = 0.f;
  for (int t = tid; t < Tout; t += 256) {
    float acc = bias;
#pragma unroll
    for (int ci = 0; ci < 6; ++ci) {
      const float* xr = xin + ((size_t)b * 6 + ci) * Tin + t;
      const float s = ssh[ci], sh = shsh[ci];
#pragma unroll
      for (int k = 0; k < 5; ++k) {
        float v = xr[k];
        if (use_aff) v = fmaxf(fmaf(s, v, sh), 0.f);
        acc += wsh[ci * 5 + k] * v;
      }
    }
    yout[((size_t)b * 6 + co) * Tout + t] = acc;
    lsum += acc; lsq += acc * acc;
  }
  __shared__ float rs[256], rq[256];
  rs[tid] = lsum; rq[tid] = lsq;
  __syncthreads();
  for (int s = 128; s > 0; s >>= 1) {
    if (tid < s) { rs[tid] += rs[tid + s]; rq[tid] += rq[tid + s]; }
    __syncthreads();
  }
  if (tid == 0) { atomicAdd(&stat[co], rs[0]); atomicAdd(&stat[6 + co], rq[0]); }
}

// ---------------- finalize BN: stats -> per-channel scale/shift ----------------
__global__ void k_finalize(const float* __restrict__ stat,
                           const float* __restrict__ gamma, const float* __restrict__ beta,
                           float* __restrict__ aff, float invN)
{
  const int c = threadIdx.x;
  if (c < 6) {
    float mean = stat[c] * invN;
    float var  = stat[6 + c] * invN - mean * mean;
    float sc   = gamma[c] * rsqrtf(var + 1e-5f);
    aff[c]     = sc;
    aff[6 + c] = fmaf(-mean, sc, beta[c]);
  }
}

// ---------------- BN2+ReLU + attn projection (6->12) + ReLU; write seq0[t][b*12+j] ----------------
__global__ void k_attn(const float* __restrict__ y2, const float* __restrict__ aff2,
                       const float* __restrict__ aw, const float* __restrict__ ab,
                       float* __restrict__ seq0)
{
  const int t = blockIdx.x;             // 0..1015
  const int tid = threadIdx.x;          // 0..767
  __shared__ float zb[6 * 64];
  if (tid < 384) {
    const int c = tid >> 6, bb = tid & 63;
    float v = y2[((size_t)bb * 6 + c) * TT + t];
    zb[c * 64 + bb] = fmaxf(fmaf(aff2[c], v, aff2[6 + c]), 0.f);
  }
  __syncthreads();
  const int b = tid / 12, j = tid - b * 12;
  float acc = ab[j];
#pragma unroll
  for (int c = 0; c < 6; ++c) acc += aw[j * 6 + c] * zb[c * 64 + b];
  seq0[(size_t)t * 768 + tid] = fmaxf(acc, 0.f);
}

// ---------------- 120-layer LSTM: 1536 self-paced single-wave blocks ----------------
// bid = chain*24 + seg. One wave = 5 layers x 12 units (lanes 60-63 pad). Diagonal:
// at step s, group p computes t = s - p. ALL intra-wave hand-off via private LDS
// (in-order DS pipe: no flags, no barriers, no fences anywhere in this kernel).
// Segment->segment: 8-step batches via L3 ring (RB=16 deep), relaxed agent atomics,
// RELEASE flag per batch. Gates pk-paired along K: pairs come directly from
// ds_read_b128 halves + preloaded weight pairs -> zero broadcast movs.
__global__ __launch_bounds__(64) void k_lstm(
    const float* __restrict__ wih, const float* __restrict__ whh,
    const float* __restrict__ bih, const float* __restrict__ bhh,
    const float* __restrict__ seq0, float* __restrict__ ring,
    int* __restrict__ prog, int* __restrict__ cons,
    float* __restrict__ hfin)
{
  const int bid   = blockIdx.x;        // 0..1535
  const int chain = bid / NSEG;        // batch element 0..63
  const int seg   = bid - chain * NSEG;
  const int lane  = threadIdx.x;       // 0..63
  const int p     = lane / 12;         // 0..5 (5 = pad)
  const int j     = lane - p * 12;
  const bool act  = (p < 5);
  const int pc    = act ? p : 0;
  const int l     = seg * 5 + pc;      // global layer

  __shared__ __align__(16) float hloc[2][64];   // double-buffered h (own wave only)
  __shared__ __align__(16) float xbuf[2][96];   // incoming x batches
  __shared__ __align__(16) float obuf[2][96];   // outgoing h staging (group 4)
  hloc[0][lane] = 0.f; hloc[1][lane] = 0.f;     // same-wave: no barrier needed

  // ---- gate weights as K-pairs: w[gate][kk] = (w[row][2kk], w[row][2kk+1]) ----
  v2f wx[4][6] = {}, wh2[4][6] = {};
  float bias[4] = {0.f, 0.f, 0.f, 0.f};
  if (act) {
    const float* wi = wih + l * 576;
    const float* wh = whh + l * 576;
#pragma unroll
    for (int q = 0; q < 4; ++q) {
      const int row = j + 12 * q;               // torch gate order i,f,g,o
#pragma unroll
      for (int kk = 0; kk < 6; ++kk) {
        wx[q][kk]  = *(const v2f*)(wi + row * 12 + 2 * kk);
        wh2[q][kk] = *(const v2f*)(wh + row * 12 + 2 * kk);
      }
      bias[q] = bih[l * 48 + row] + bhh[l * 48 + row];
    }
  }

  const int hop_in  = chain * HOPS + seg - 1;   // valid if seg>0
  const int hop_out = chain * HOPS + seg;       // valid if seg<23
  const bool has_up = (seg > 0), has_dn = (seg < HOPS);
  const float* rin  = ring + (size_t)(has_up ? hop_in : 0) * (RB * 96);
  float*       rout = ring + (size_t)(has_dn ? hop_out : 0) * (RB * 96);

  const int g0 = (lane / 12) * 768 + (lane % 12);             // seq0 gather offsets
  const int g1 = ((64 + lane) / 12) * 768 + ((64 + lane) % 12);

  auto ld_batch = [&](int m, float& d0, float& d1) {
    if (seg == 0) {
      const float* b = seq0 + (size_t)(m * 8) * 768 + chain * 12;
      d0 = b[g0];
      if (lane < 32) d1 = b[g1];
    } else {
      const float* b = rin + (m & (RB - 1)) * 96;
      d0 = __hip_atomic_load(b + lane, __ATOMIC_RELAXED, __HIP_MEMORY_SCOPE_AGENT);
      if (lane < 32) d1 = __hip_atomic_load(b + 64 + lane, __ATOMIC_RELAXED, __HIP_MEMORY_SCOPE_AGENT);
    }
  };

  // ---- prologue: batch 0 -> xbuf[0], batch 1 -> pend ----
  int kp = 0, kc = 0;
  float p0 = 0.f, p1 = 0.f;
  {
    if (has_up) kp = poll_ge_ag(&prog[hop_in], 2, 0);
    float c0 = 0.f, c1 = 0.f;
    ld_batch(0, c0, c1);
    xbuf[0][lane] = c0;
    if (lane < 32) xbuf[0][64 + lane] = c1;
    ld_batch(1, p0, p1);
  }

  float cst = 0.f, hn = 0.f;

  auto step = [&](int s, bool guard) __attribute__((always_inline)) {
    const int rb = (s & 1) ^ 1, wb = s & 1;
    const float* bx = (p == 0) ? &xbuf[(s >> 3) & 1][(s & 7) * 12]
                               : &hloc[rb][(pc ? pc - 1 : 0) * 12];
    const float* bh = &hloc[rb][pc * 12];
    float4 x0 = ((const float4*)bx)[0], x1 = ((const float4*)bx)[1], x2 = ((const float4*)bx)[2];
    float4 h0 = ((const float4*)bh)[0], h1 = ((const float4*)bh)[1], h2 = ((const float4*)bh)[2];
    v2f px[6] = {{x0.x,x0.y},{x0.z,x0.w},{x1.x,x1.y},{x1.z,x1.w},{x2.x,x2.y},{x2.z,x2.w}};
    v2f ph[6] = {{h0.x,h0.y},{h0.z,h0.w},{h1.x,h1.y},{h1.z,h1.w},{h2.x,h2.y},{h2.z,h2.w}};

    v2f a0 = {bias[0], 0.f}, a1 = {bias[1], 0.f}, a2 = {bias[2], 0.f}, a3 = {bias[3], 0.f};
#pragma unroll
    for (int kk = 0; kk < 6; ++kk) {
      a0 = __builtin_elementwise_fma(wx[0][kk], px[kk], a0);
      a1 = __builtin_elementwise_fma(wx[1][kk], px[kk], a1);
      a2 = __builtin_elementwise_fma(wx[2][kk], px[kk], a2);
      a3 = __builtin_elementwise_fma(wx[3][kk], px[kk], a3);
    }
#pragma unroll
    for (int kk = 0; kk < 6; ++kk) {
      a0 = __builtin_elementwise_fma(wh2[0][kk], ph[kk], a0);
      a1 = __builtin_elementwise_fma(wh2[1][kk], ph[kk], a1);
      a2 = __builtin_elementwise_fma(wh2[2][kk], ph[kk], a2);
      a3 = __builtin_elementwise_fma(wh2[3][kk], ph[kk], a3);
    }
    float ig = fast_sig(a0.x + a0.y);
    float fg = fast_sig(a1.x + a1.y);
    float gv = fast_tanh(a2.x + a2.y);
    float og = fast_sig(a3.x + a3.y);

    if (!guard) {
      cst = fg * cst + ig * gv;
      hn  = og * fast_tanh(cst);
      hloc[wb][lane] = hn;
      if (p == 4) obuf[((s - 4) >> 3) & 1][((s - 4) & 7) * 12 + j] = hn;
    } else {
      const int t = s - pc;
      const bool run = act && (t >= 0) && (t < TT);
      if (run) {
        cst = fg * cst + ig * gv;
        hn  = og * fast_tanh(cst);
      }
      hloc[wb][lane] = hn;     // stale rewrite when !run keeps buffers consistent (0 at start)
      if (p == 4 && t >= 0 && t < TT) obuf[(t >> 3) & 1][(t & 7) * 12 + j] = hn;
      if (run && t == TT - 1) hfin[l * 768 + chain * 12 + j] = hn;
    }
    __builtin_amdgcn_wave_barrier();   // compile-time only: pin DS order, no instruction
  };

  for (int s8 = 0; s8 < 1024; s8 += 8) {
    const int m = s8 >> 3;

    // (1) publish pend (batch m+1) -> xbuf
    if (m + 1 <= NBAT - 1) {
      float* xd = &xbuf[(m + 1) & 1][0];
      xd[lane] = p0;
      if (lane < 32) xd[64 + lane] = p1;
    }
    // (2) flush batch m-2 + RELEASE (before new loads, so the drain only covers these stores)
    if (has_dn && m >= 2) {
      const int b = m - 2;
      if (kc < b - (RB - 1)) kc = poll_ge_ag(&cons[hop_out], b - (RB - 1), kc);
      const float* orf = &obuf[b & 1][0];
      float o0 = orf[lane];
      float o1 = (lane < 32) ? orf[64 + lane] : 0.f;
      float* d = rout + (b & (RB - 1)) * 96;
      __hip_atomic_store(d + lane, o0, __ATOMIC_RELAXED, __HIP_MEMORY_SCOPE_AGENT);
      if (lane < 32)
        __hip_atomic_store(d + 64 + lane, o1, __ATOMIC_RELAXED, __HIP_MEMORY_SCOPE_AGENT);
      if (lane == 0)
        __hip_atomic_store(&prog[hop_out], b + 1, __ATOMIC_RELEASE, __HIP_MEMORY_SCOPE_AGENT);
    }
    // (3) consumed-count post
    if (has_up && lane == 0)
      __hip_atomic_store(&cons[hop_in], m + 2, __ATOMIC_RELAXED, __HIP_MEMORY_SCOPE_AGENT);
    // (4) start loads for batch m+2 (in flight for the next 8 steps)
    if (m + 2 <= NBAT - 1) {
      if (has_up && kp < m + 3) kp = poll_ge_ag(&prog[hop_in], m + 3, kp);
      ld_batch(m + 2, p0, p1);
    }

    if (s8 >= 8 && s8 < 1008) {
      step(s8 + 0, false); step(s8 + 1, false); step(s8 + 2, false); step(s8 + 3, false);
      step(s8 + 4, false); step(s8 + 5, false); step(s8 + 6, false); step(s8 + 7, false);
    } else {
      step(s8 + 0, true);  step(s8 + 1, true);  step(s8 + 2, true);  step(s8 + 3, true);
      step(s8 + 4, true);  step(s8 + 5, true);  step(s8 + 6, true);  step(s8 + 7, true);
    }
  }

  // ---- epilogue: flush final batch 126 ----
  if (has_dn) {
    const int b = NBAT - 1;   // 126
    const float* orf = &obuf[b & 1][0];
    float o0 = orf[lane];
    float o1 = (lane < 32) ? orf[64 + lane] : 0.f;
    float* d = rout + (b & (RB - 1)) * 96;
    __hip_atomic_store(d + lane, o0, __ATOMIC_RELAXED, __HIP_MEMORY_SCOPE_AGENT);
    if (lane < 32)
      __hip_atomic_store(d + 64 + lane, o1, __ATOMIC_RELAXED, __HIP_MEMORY_SCOPE_AGENT);
    if (lane == 0)
      __hip_atomic_store(&prog[hop_out], b + 1, __ATOMIC_RELEASE, __HIP_MEMORY_SCOPE_AGENT);
  }
}

// ---------------- head: lin1+relu, lin2+relu, mu, softplus(sigma) ----------------
__global__ void k_head(const float* __restrict__ hfin,
                       const float* __restrict__ w1, const float* __restrict__ b1,
                       const float* __restrict__ w2, const float* __restrict__ b2,
                       const float* __restrict__ wm, const float* __restrict__ bm,
                       const float* __restrict__ wsg, const float* __restrict__ bsg,
                       float* __restrict__ out)
{
  const int tid = threadIdx.x;
  __shared__ float s1[144], s2[144], sm[144], ss[144];
  __shared__ float v1[12], v2[12], vm[12], vs[12];
  if (tid < 144) { s1[tid] = w1[tid]; s2[tid] = w2[tid]; sm[tid] = wm[tid]; ss[tid] = wsg[tid]; }
  if (tid < 12)  { v1[tid] = b1[tid]; v2[tid] = b2[tid]; vm[tid] = bm[tid]; vs[tid] = bsg[tid]; }
  __syncthreads();
  const int r = blockIdx.x * 256 + tid;   // 0..7679 = b*120 + l
  const int b = r / 120, l = r - b * 120;
  float h[12];
#pragma unroll
  for (int k = 0; k < 12; ++k) h[k] = hfin[l * 768 + b * 12 + k];
  float u1[12];
#pragma unroll
  for (int u = 0; u < 12; ++u) {
    float a = v1[u];
#pragma unroll
    for (int k = 0; k < 12; ++k) a += s1[u * 12 + k] * h[k];
    u1[u] = fmaxf(a, 0.f);
  }
  float u2[12];
#pragma unroll
  for (int u = 0; u < 12; ++u) {
    float a = v2[u];
#pragma unroll
    for (int k = 0; k < 12; ++k) a += s2[u * 12 + k] * u1[k];
    u2[u] = fmaxf(a, 0.f);
  }
  const size_t base = (size_t)r * 12;
#pragma unroll
  for (int u = 0; u < 12; ++u) out[base + u] = u2[u];
#pragma unroll
  for (int u = 0; u < 12; ++u) {
    float a = vm[u];
#pragma unroll
    for (int k = 0; k < 12; ++k) a += sm[u * 12 + k] * u2[k];
    out[92160 + base + u] = a;
  }
#pragma unroll
  for (int u = 0; u < 12; ++u) {
    float a = vs[u];
#pragma unroll
    for (int k = 0; k < 12; ++k) a += ss[u * 12 + k] * u2[k];
    out[184320 + base + u] = fmaxf(a, 0.f) + log1pf(expf(-fabsf(a)));
  }
}

// ---------------- launcher ----------------
extern "C" void kernel_launch(void* const* d_in, const int* in_sizes, int n_in,
                              void* d_out, int out_size, void* d_ws, size_t ws_size,
                              hipStream_t stream)
{
  const float* x   = (const float*)d_in[0];
  const float* c1w = (const float*)d_in[1];
  const float* c1b = (const float*)d_in[2];
  const float* g1  = (const float*)d_in[3];
  const float* be1 = (const float*)d_in[4];
  const float* c2w = (const float*)d_in[5];
  const float* c2b = (const float*)d_in[6];
  const float* g2  = (const float*)d_in[7];
  const float* be2 = (const float*)d_in[8];
  const float* aw  = (const float*)d_in[9];
  const float* ab  = (const float*)d_in[10];
  const float* wih = (const float*)d_in[11];
  const float* whh = (const float*)d_in[12];
  const float* bih = (const float*)d_in[13];
  const float* bhh = (const float*)d_in[14];
  const float* l1w = (const float*)d_in[15];
  const float* l1b = (const float*)d_in[16];
  const float* l2w = (const float*)d_in[17];
  const float* l2b = (const float*)d_in[18];
  const float* muw = (const float*)d_in[19];
  const float* mub = (const float*)d_in[20];
  const float* sgw = (const float*)d_in[21];
  const float* sgb = (const float*)d_in[22];

  float* ws    = (float*)d_ws;
  float* stat1 = ws;                    // 12
  float* stat2 = ws + 12;               // 12
  float* aff1  = ws + 24;               // 12
  float* aff2  = ws + 36;               // 12
  int*   prog  = (int*)(ws + 64);       // 64*23 = 1472 ints
  int*   cons  = (int*)(ws + 64 + 1472);// 1472 ints
  float* y1    = ws + 3072;             // 64*6*1020
  float* y2    = y1 + 391680;           // 64*6*1016
  float* seq0  = y2 + 390144;           // 1016*768
  float* ring  = seq0 + 780288;         // 1472 hops * 16 slots * 96 floats (+64 pad)
  float* hfin  = ring + (size_t)1472 * RB * 96 + 64;   // 120*768

  hipMemsetAsync(d_ws, 0, 3072 * sizeof(float), stream);  // zero stats + flags

  k_conv<<<384, 256, 0, stream>>>(x, c1w, c1b, nullptr, y1, stat1, 1024, 1020, 0);
  k_finalize<<<1, 64, 0, stream>>>(stat1, g1, be1, aff1, 1.f / 65280.f);
  k_conv<<<384, 256, 0, stream>>>(y1, c2w, c2b, aff1, y2, stat2, 1020, 1016, 1);
  k_finalize<<<1, 64, 0, stream>>>(stat2, g2, be2, aff2, 1.f / 65024.f);
  k_attn<<<1016, 768, 0, stream>>>(y2, aff2, aw, ab, seq0);
  k_lstm<<<1536, 64, 0, stream>>>(wih, whh, bih, bhh, seq0, ring, prog, cons, hfin);
  k_head<<<30, 256, 0, stream>>>(hfin, l1w, l1b, l2w, l2b, muw, mub, sgw, sgb, (float*)d_out);
}

// Round 8
// 1360.265 us; speedup vs baseline: 2.0075x; 2.0075x over previous
//
#include <hip/hip_runtime.h>
#include <math.h>

// ---------------- problem constants ----------------
#define NLAY 120         // LSTM layers
#define TT   1016        // LSTM time steps (1024 - 4 - 4)
#define NB   64          // batches of 16 steps
#define RB   8           // L3 ring depth in batches (power of 2)
#define IRS  32          // inter-wave LDS ring slots (power of 2)
#define TPB  384         // 6 waves; wave = 5 layers x 12 units (lanes 60-63 pad), x2 chains

typedef float v2f __attribute__((ext_vector_type(2)));

__device__ __forceinline__ float fast_rcp(float x) { return __builtin_amdgcn_rcpf(x); }
__device__ __forceinline__ float fast_sig(float x) { return fast_rcp(1.f + __expf(-x)); }
__device__ __forceinline__ float fast_tanh(float x) { return 1.f - 2.f * fast_rcp(1.f + __expf(2.f * x)); }

__device__ __forceinline__ int poll_ge_ag(const int* p, int tgt, int cur) {
  long g = 0;
  while (cur < tgt) {
    cur = __hip_atomic_load(p, __ATOMIC_RELAXED, __HIP_MEMORY_SCOPE_AGENT);
    if (cur >= tgt) break;
    __builtin_amdgcn_s_sleep(1);
    if (++g > 400000L) break;   // fail loud, never hang
  }
  return cur;
}
__device__ __forceinline__ int poll_ge_wg(const int* p, int tgt, int cur) {
  long g = 0;
  while (cur < tgt) {
    cur = __hip_atomic_load(p, __ATOMIC_RELAXED, __HIP_MEMORY_SCOPE_WORKGROUP);
    if (cur >= tgt) break;
    __builtin_amdgcn_s_sleep(1);
    if (++g > 400000L) break;
  }
  return cur;
}

// ---------------- conv1d(6->6,K=5,valid) + bias, accumulate BN stats ----------------
__global__ void k_conv(const float* __restrict__ xin, const float* __restrict__ cw,
                       const float* __restrict__ cb, const float* __restrict__ aff,
                       float* __restrict__ yout, float* __restrict__ stat,
                       int Tin, int Tout, int use_aff)
{
  const int bx = blockIdx.x;
  const int b = bx / 6, co = bx - b * 6;
  const int tid = threadIdx.x;
  __shared__ float wsh[30];
  __shared__ float ssh[6], shsh[6];
  if (tid < 30) wsh[tid] = cw[co * 30 + tid];
  if (tid < 6) {
    ssh[tid]  = use_aff ? aff[tid] : 1.f;
    shsh[tid] = use_aff ? aff[6 + tid] : 0.f;
  }
  __syncthreads();
  const float bias = cb[co];
  float lsum = 0.f, lsq = 0.f;
  for (int t = tid; t < Tout; t += 256) {
    float acc = bias;
#pragma unroll
    for (int ci = 0; ci < 6; ++ci) {
      const float* xr = xin + ((size_t)b * 6 + ci) * Tin + t;
      const float s = ssh[ci], sh = shsh[ci];
#pragma unroll
      for (int k = 0; k < 5; ++k) {
        float v = xr[k];
        if (use_aff) v = fmaxf(fmaf(s, v, sh), 0.f);
        acc += wsh[ci * 5 + k] * v;
      }
    }
    yout[((size_t)b * 6 + co) * Tout + t] = acc;
    lsum += acc; lsq += acc * acc;
  }
  __shared__ float rs[256], rq[256];
  rs[tid] = lsum; rq[tid] = lsq;
  __syncthreads();
  for (int s = 128; s > 0; s >>= 1) {
    if (tid < s) { rs[tid] += rs[tid + s]; rq[tid] += rq[tid + s]; }
    __syncthreads();
  }
  if (tid == 0) { atomicAdd(&stat[co], rs[0]); atomicAdd(&stat[6 + co], rq[0]); }
}

__global__ void k_finalize(const float* __restrict__ stat,
                           const float* __restrict__ gamma, const float* __restrict__ beta,
                           float* __restrict__ aff, float invN)
{
  const int c = threadIdx.x;
  if (c < 6) {
    float mean = stat[c] * invN;
    float var  = stat[6 + c] * invN - mean * mean;
    float sc   = gamma[c] * rsqrtf(var + 1e-5f);
    aff[c]     = sc;
    aff[6 + c] = fmaf(-mean, sc, beta[c]);
  }
}

__global__ void k_attn(const float* __restrict__ y2, const float* __restrict__ aff2,
                       const float* __restrict__ aw, const float* __restrict__ ab,
                       float* __restrict__ seq0)
{
  const int t = blockIdx.x;
  const int tid = threadIdx.x;
  __shared__ float zb[6 * 64];
  if (tid < 384) {
    const int c = tid >> 6, bb = tid & 63;
    float v = y2[((size_t)bb * 6 + c) * TT + t];
    zb[c * 64 + bb] = fmaxf(fmaf(aff2[c], v, aff2[6 + c]), 0.f);
  }
  __syncthreads();
  const int b = tid / 12, j = tid - b * 12;
  float acc = ab[j];
#pragma unroll
  for (int c = 0; c < 6; ++c) acc += aw[j * 6 + c] * zb[c * 64 + b];
  seq0[(size_t)t * 768 + tid] = fmaxf(acc, 0.f);
}

// ---------------- 120-layer LSTM: 128 blocks, 6 waves, TWO chains per wave ----------------
// bid = cb*4 + seg; cb = chain-pair (chains 2cb, 2cb+1), seg = 30 layers. Wave w = 5-layer
// stage, lane (p,j) = layer w*5+p, unit j. Diagonal: group p computes t = s - p.
// Two independent recurrences (A,B) interleaved per step hide LDS/transcendental latency.
// Wave->wave: iring + relaxed LDS flags, cadence 8. Block->block: 16-step L3 ring batches.
__global__ __launch_bounds__(TPB, 2) void k_lstm(
    const float* __restrict__ wih, const float* __restrict__ whh,
    const float* __restrict__ bih, const float* __restrict__ bhh,
    const float* __restrict__ seq0, float* __restrict__ ring,
    int* __restrict__ prog, int* __restrict__ cons,
    float* __restrict__ hfin)
{
  const int bid  = blockIdx.x;         // 0..127
  const int cb   = bid >> 2;           // chain pair 0..31
  const int seg  = bid & 3;
  const int cA   = cb * 2, cB = cb * 2 + 1;
  const int tid  = threadIdx.x;
  const int w    = tid >> 6;           // wave 0..5
  const int lane = tid & 63;
  const int p    = lane / 12;          // 0..5 (5 = pad)
  const int j    = lane - p * 12;
  const bool act = (p < 5);
  const int pc   = act ? p : 0;
  const int l    = seg * 30 + w * 5 + pc;

  // ---- LDS ----
  __shared__ __align__(16) float hlocA[6][2][64], hlocB[6][2][64];
  __shared__ __align__(16) float iringA[5][IRS][12], iringB[5][IRS][12];
  __shared__ __align__(16) float xrA[2][192], xrB[2][192];
  __shared__ __align__(16) float obA[2][192], obB[2][192];
  __shared__ int pflag[8], cflag[8];

  if (tid < 8) { pflag[tid] = 0; cflag[tid] = 0; }
  hlocA[w][0][lane] = 0.f; hlocA[w][1][lane] = 0.f;
  hlocB[w][0][lane] = 0.f; hlocB[w][1][lane] = 0.f;
  __syncthreads();   // only barrier in the kernel

  // ---- gate weights as K-pairs (shared by both chains) ----
  v2f wx[4][6] = {}, wh2[4][6] = {};
  float bias[4] = {0.f, 0.f, 0.f, 0.f};
  if (act) {
    const float* wi = wih + l * 576;
    const float* wh = whh + l * 576;
#pragma unroll
    for (int q = 0; q < 4; ++q) {
      const int row = j + 12 * q;   // torch gate order i,f,g,o
#pragma unroll
      for (int kk = 0; kk < 6; ++kk) {
        wx[q][kk]  = *(const v2f*)(wi + row * 12 + 2 * kk);
        wh2[q][kk] = *(const v2f*)(wh + row * 12 + 2 * kk);
      }
      bias[q] = bih[l * 48 + row] + bhh[l * 48 + row];
    }
  }

  // ---- inter-segment plumbing (per chain) ----
  const int hopAi = cA * 3 + seg - 1, hopBi = cB * 3 + seg - 1;  // valid if seg>0
  const int hopAo = cA * 3 + seg,     hopBo = cB * 3 + seg;      // valid if seg<3
  const bool has_up = (seg > 0), has_dn = (seg < 3);
  const float* rinA = ring + (size_t)(has_up ? hopAi : 0) * (RB * 192);
  const float* rinB = ring + (size_t)(has_up ? hopBi : 0) * (RB * 192);
  float* routA = ring + (size_t)(has_dn ? hopAo : 0) * (RB * 192);
  float* routB = ring + (size_t)(has_dn ? hopBo : 0) * (RB * 192);
  const bool is_feeder = (w == 0);
  const bool is_tailer = (w == 5) && has_dn;

  const int f0 = lane, f1 = lane + 64, f2 = lane + 128;
  const int s0o0 = (f0 / 12) * 768 + (f0 % 12);
  const int s0o1 = (f1 / 12) * 768 + (f1 % 12);
  const int s0o2 = (f2 / 12) * 768 + (f2 % 12);

  auto ld_batch = [&](int m, const float* rin, int chain, float* d) {
    if (seg == 0) {
      const float* b = seq0 + (size_t)m * 16 * 768 + chain * 12;
      d[0] = b[s0o0]; d[1] = b[s0o1]; d[2] = b[s0o2];
    } else {
      const float* b = rin + (m & (RB - 1)) * 192;
      d[0] = __hip_atomic_load(b + f0, __ATOMIC_RELAXED, __HIP_MEMORY_SCOPE_AGENT);
      d[1] = __hip_atomic_load(b + f1, __ATOMIC_RELAXED, __HIP_MEMORY_SCOPE_AGENT);
      d[2] = __hip_atomic_load(b + f2, __ATOMIC_RELAXED, __HIP_MEMORY_SCOPE_AGENT);
    }
  };

  float pendA[3] = {0,0,0}, pendB[3] = {0,0,0};
  int kpA = 0, kpB = 0, kcA = 0, kcB = 0;
  if (is_feeder) {
    if (has_up) { kpA = poll_ge_ag(&prog[hopAi], 2, 0); kpB = poll_ge_ag(&prog[hopBi], 2, 0); }
    float curA[3], curB[3];
    ld_batch(0, rinA, cA, curA); ld_batch(0, rinB, cB, curB);
    xrA[0][f0] = curA[0]; xrA[0][f1] = curA[1]; xrA[0][f2] = curA[2];
    xrB[0][f0] = curB[0]; xrB[0][f1] = curB[1]; xrB[0][f2] = curB[2];
    ld_batch(1, rinA, cA, pendA); ld_batch(1, rinB, cB, pendB);
  }

  float cstA = 0.f, hnA = 0.f, cstB = 0.f, hnB = 0.f;
  int pcache = 0, ccache = 0;

  auto step = [&](int s, bool guard) __attribute__((always_inline)) {
    const int rb = (s & 1) ^ 1, wb = s & 1;
    const float* bxA;
    const float* bxB;
    if (p == 0) {
      if (w == 0) { bxA = &xrA[(s >> 4) & 1][(s & 15) * 12]; bxB = &xrB[(s >> 4) & 1][(s & 15) * 12]; }
      else        { bxA = &iringA[w - 1][s & (IRS - 1)][0];  bxB = &iringB[w - 1][s & (IRS - 1)][0]; }
    } else {
      bxA = &hlocA[w][rb][(pc ? pc - 1 : 0) * 12];
      bxB = &hlocB[w][rb][(pc ? pc - 1 : 0) * 12];
    }
    const float* bhA = &hlocA[w][rb][pc * 12];
    const float* bhB = &hlocB[w][rb][pc * 12];
    float4 xA0=((const float4*)bxA)[0], xA1=((const float4*)bxA)[1], xA2=((const float4*)bxA)[2];
    float4 hA0=((const float4*)bhA)[0], hA1=((const float4*)bhA)[1], hA2=((const float4*)bhA)[2];
    float4 xB0=((const float4*)bxB)[0], xB1=((const float4*)bxB)[1], xB2=((const float4*)bxB)[2];
    float4 hB0=((const float4*)bhB)[0], hB1=((const float4*)bhB)[1], hB2=((const float4*)bhB)[2];
    v2f pxA[6]={{xA0.x,xA0.y},{xA0.z,xA0.w},{xA1.x,xA1.y},{xA1.z,xA1.w},{xA2.x,xA2.y},{xA2.z,xA2.w}};
    v2f phA[6]={{hA0.x,hA0.y},{hA0.z,hA0.w},{hA1.x,hA1.y},{hA1.z,hA1.w},{hA2.x,hA2.y},{hA2.z,hA2.w}};
    v2f pxB[6]={{xB0.x,xB0.y},{xB0.z,xB0.w},{xB1.x,xB1.y},{xB1.z,xB1.w},{xB2.x,xB2.y},{xB2.z,xB2.w}};
    v2f phB[6]={{hB0.x,hB0.y},{hB0.z,hB0.w},{hB1.x,hB1.y},{hB1.z,hB1.w},{hB2.x,hB2.y},{hB2.z,hB2.w}};

    v2f aA0={bias[0],0.f}, aA1={bias[1],0.f}, aA2={bias[2],0.f}, aA3={bias[3],0.f};
    v2f aB0={bias[0],0.f}, aB1={bias[1],0.f}, aB2={bias[2],0.f}, aB3={bias[3],0.f};
#pragma unroll
    for (int kk = 0; kk < 6; ++kk) {
      aA0 = __builtin_elementwise_fma(wx[0][kk], pxA[kk], aA0);
      aB0 = __builtin_elementwise_fma(wx[0][kk], pxB[kk], aB0);
      aA1 = __builtin_elementwise_fma(wx[1][kk], pxA[kk], aA1);
      aB1 = __builtin_elementwise_fma(wx[1][kk], pxB[kk], aB1);
      aA2 = __builtin_elementwise_fma(wx[2][kk], pxA[kk], aA2);
      aB2 = __builtin_elementwise_fma(wx[2][kk], pxB[kk], aB2);
      aA3 = __builtin_elementwise_fma(wx[3][kk], pxA[kk], aA3);
      aB3 = __builtin_elementwise_fma(wx[3][kk], pxB[kk], aB3);
    }
#pragma unroll
    for (int kk = 0; kk < 6; ++kk) {
      aA0 = __builtin_elementwise_fma(wh2[0][kk], phA[kk], aA0);
      aB0 = __builtin_elementwise_fma(wh2[0][kk], phB[kk], aB0);
      aA1 = __builtin_elementwise_fma(wh2[1][kk], phA[kk], aA1);
      aB1 = __builtin_elementwise_fma(wh2[1][kk], phB[kk], aB1);
      aA2 = __builtin_elementwise_fma(wh2[2][kk], phA[kk], aA2);
      aB2 = __builtin_elementwise_fma(wh2[2][kk], phB[kk], aB2);
      aA3 = __builtin_elementwise_fma(wh2[3][kk], phA[kk], aA3);
      aB3 = __builtin_elementwise_fma(wh2[3][kk], phB[kk], aB3);
    }
    float igA = fast_sig(aA0.x + aA0.y), igB = fast_sig(aB0.x + aB0.y);
    float fgA = fast_sig(aA1.x + aA1.y), fgB = fast_sig(aB1.x + aB1.y);
    float gvA = fast_tanh(aA2.x + aA2.y), gvB = fast_tanh(aB2.x + aB2.y);
    float ogA = fast_sig(aA3.x + aA3.y), ogB = fast_sig(aB3.x + aB3.y);

    if (!guard) {
      cstA = fgA * cstA + igA * gvA;  cstB = fgB * cstB + igB * gvB;
      hnA  = ogA * fast_tanh(cstA);   hnB  = ogB * fast_tanh(cstB);
      hlocA[w][wb][lane] = hnA;       hlocB[w][wb][lane] = hnB;
      if (p == 4) {
        const int t = s - 4;
        if (w < 5) { iringA[w][t & (IRS - 1)][j] = hnA; iringB[w][t & (IRS - 1)][j] = hnB; }
        else if (has_dn) {
          obA[(t >> 4) & 1][(t & 15) * 12 + j] = hnA;
          obB[(t >> 4) & 1][(t & 15) * 12 + j] = hnB;
        }
      }
    } else {
      const int t = s - pc;
      const bool run = act && (t >= 0) && (t < TT);
      if (run) {
        cstA = fgA * cstA + igA * gvA;  cstB = fgB * cstB + igB * gvB;
        hnA  = ogA * fast_tanh(cstA);   hnB  = ogB * fast_tanh(cstB);
      }
      hlocA[w][wb][lane] = hnA; hlocB[w][wb][lane] = hnB;
      if (p == 4 && t >= 0 && t < TT) {
        if (w < 5) { iringA[w][t & (IRS - 1)][j] = hnA; iringB[w][t & (IRS - 1)][j] = hnB; }
        else if (has_dn) {
          obA[(t >> 4) & 1][(t & 15) * 12 + j] = hnA;
          obB[(t >> 4) & 1][(t & 15) * 12 + j] = hnB;
        }
      }
      if (run && t == TT - 1) {
        hfin[l * 768 + cA * 12 + j] = hnA;
        hfin[l * 768 + cB * 12 + j] = hnB;
      }
    }
    __builtin_amdgcn_wave_barrier();   // compile-time DS-order pin, no instruction
  };

  auto flush = [&](int b) {            // tailer: ship batch b of both chains
    if (kcA < b - (RB - 1)) kcA = poll_ge_ag(&cons[hopAo], b - (RB - 1), kcA);
    if (kcB < b - (RB - 1)) kcB = poll_ge_ag(&cons[hopBo], b - (RB - 1), kcB);
    const float* oa = &obA[b & 1][0];
    const float* ob = &obB[b & 1][0];
    float a0 = oa[f0], a1 = oa[f1], a2 = oa[f2];
    float b0 = ob[f0], b1 = ob[f1], b2 = ob[f2];
    float* dA = routA + (b & (RB - 1)) * 192;
    float* dB = routB + (b & (RB - 1)) * 192;
    __hip_atomic_store(dA + f0, a0, __ATOMIC_RELAXED, __HIP_MEMORY_SCOPE_AGENT);
    __hip_atomic_store(dA + f1, a1, __ATOMIC_RELAXED, __HIP_MEMORY_SCOPE_AGENT);
    __hip_atomic_store(dA + f2, a2, __ATOMIC_RELAXED, __HIP_MEMORY_SCOPE_AGENT);
    __hip_atomic_store(dB + f0, b0, __ATOMIC_RELAXED, __HIP_MEMORY_SCOPE_AGENT);
    __hip_atomic_store(dB + f1, b1, __ATOMIC_RELAXED, __HIP_MEMORY_SCOPE_AGENT);
    __hip_atomic_store(dB + f2, b2, __ATOMIC_RELAXED, __HIP_MEMORY_SCOPE_AGENT);
    if (lane == 0) {   // first RELEASE drains all 6 stores; second is free
      __hip_atomic_store(&prog[hopAo], b + 1, __ATOMIC_RELEASE, __HIP_MEMORY_SCOPE_AGENT);
      __hip_atomic_store(&prog[hopBo], b + 1, __ATOMIC_RELEASE, __HIP_MEMORY_SCOPE_AGENT);
    }
  };

  for (int s8 = 0; s8 < 1024; s8 += 8) {
    // ---- feeder: every 16 steps publish batch m+1, start loads for m+2 ----
    if (is_feeder && (s8 & 15) == 0) {
      const int m = s8 >> 4;
      if (m + 1 < NB) {
        float* xa = &xrA[(m + 1) & 1][0];
        float* xb = &xrB[(m + 1) & 1][0];
        xa[f0] = pendA[0]; xa[f1] = pendA[1]; xa[f2] = pendA[2];
        xb[f0] = pendB[0]; xb[f1] = pendB[1]; xb[f2] = pendB[2];
      }
      if (has_up && lane == 0) {
        __hip_atomic_store(&cons[hopAi], m, __ATOMIC_RELAXED, __HIP_MEMORY_SCOPE_AGENT);
        __hip_atomic_store(&cons[hopBi], m, __ATOMIC_RELAXED, __HIP_MEMORY_SCOPE_AGENT);
      }
      if (m + 2 < NB) {
        if (has_up) {
          const int tgt = (m + 3 < NB) ? m + 3 : NB;
          if (kpA < tgt) kpA = poll_ge_ag(&prog[hopAi], tgt, kpA);
          if (kpB < tgt) kpB = poll_ge_ag(&prog[hopBi], tgt, kpB);
        }
        ld_batch(m + 2, rinA, cA, pendA);
        ld_batch(m + 2, rinB, cB, pendB);
      }
    }
    // ---- tailer: flush batch (s8-24)/16 when s8 = 16b+24 ----
    if (is_tailer && (s8 & 15) == 8 && s8 >= 24) flush((s8 - 24) >> 4);

    // ---- wave-to-wave flags, cadence 8 ----
    if (w > 0) {
      const int tgt = (s8 + 12 < 1020) ? s8 + 12 : 1020;
      if (pcache < tgt) {
        pcache = poll_ge_wg(&pflag[w - 1], tgt, pcache);
        asm volatile("" ::: "memory");
      }
    }
    if (w < 5 && s8 >= 32) {
      const int tgt = s8 - 24;
      if (ccache < tgt) {
        ccache = poll_ge_wg(&cflag[w + 1], tgt, ccache);
        asm volatile("" ::: "memory");
      }
    }

    if (s8 >= 8 && s8 < 1008) {
      step(s8 + 0, false); step(s8 + 1, false); step(s8 + 2, false); step(s8 + 3, false);
      step(s8 + 4, false); step(s8 + 5, false); step(s8 + 6, false); step(s8 + 7, false);
    } else {
      step(s8 + 0, true);  step(s8 + 1, true);  step(s8 + 2, true);  step(s8 + 3, true);
      step(s8 + 4, true);  step(s8 + 5, true);  step(s8 + 6, true);  step(s8 + 7, true);
    }

    if (lane == 0) {
      asm volatile("" ::: "memory");
      if (w < 5) __hip_atomic_store(&pflag[w], s8 + 8, __ATOMIC_RELAXED, __HIP_MEMORY_SCOPE_WORKGROUP);
      if (w > 0) __hip_atomic_store(&cflag[w], s8 + 8, __ATOMIC_RELAXED, __HIP_MEMORY_SCOPE_WORKGROUP);
    }
  }

  // ---- epilogue: tailer ships the final batch (63) ----
  if (is_tailer) flush(NB - 1);
}

// ---------------- head: lin1+relu, lin2+relu, mu, softplus(sigma) ----------------
__global__ void k_head(const float* __restrict__ hfin,
                       const float* __restrict__ w1, const float* __restrict__ b1,
                       const float* __restrict__ w2, const float* __restrict__ b2,
                       const float* __restrict__ wm, const float* __restrict__ bm,
                       const float* __restrict__ wsg, const float* __restrict__ bsg,
                       float* __restrict__ out)
{
  const int tid = threadIdx.x;
  __shared__ float s1[144], s2[144], sm[144], ss[144];
  __shared__ float v1[12], v2[12], vm[12], vs[12];
  if (tid < 144) { s1[tid] = w1[tid]; s2[tid] = w2[tid]; sm[tid] = wm[tid]; ss[tid] = wsg[tid]; }
  if (tid < 12)  { v1[tid] = b1[tid]; v2[tid] = b2[tid]; vm[tid] = bm[tid]; vs[tid] = bsg[tid]; }
  __syncthreads();
  const int r = blockIdx.x * 256 + tid;
  const int b = r / 120, l = r - b * 120;
  float h[12];
#pragma unroll
  for (int k = 0; k < 12; ++k) h[k] = hfin[l * 768 + b * 12 + k];
  float u1[12];
#pragma unroll
  for (int u = 0; u < 12; ++u) {
    float a = v1[u];
#pragma unroll
    for (int k = 0; k < 12; ++k) a += s1[u * 12 + k] * h[k];
    u1[u] = fmaxf(a, 0.f);
  }
  float u2[12];
#pragma unroll
  for (int u = 0; u < 12; ++u) {
    float a = v2[u];
#pragma unroll
    for (int k = 0; k < 12; ++k) a += s2[u * 12 + k] * u1[k];
    u2[u] = fmaxf(a, 0.f);
  }
  const size_t base = (size_t)r * 12;
#pragma unroll
  for (int u = 0; u < 12; ++u) out[base + u] = u2[u];
#pragma unroll
  for (int u = 0; u < 12; ++u) {
    float a = vm[u];
#pragma unroll
    for (int k = 0; k < 12; ++k) a += sm[u * 12 + k] * u2[k];
    out[92160 + base + u] = a;
  }
#pragma unroll
  for (int u = 0; u < 12; ++u) {
    float a = vs[u];
#pragma unroll
    for (int k = 0; k < 12; ++k) a += ss[u * 12 + k] * u2[k];
    out[184320 + base + u] = fmaxf(a, 0.f) + log1pf(expf(-fabsf(a)));
  }
}

// ---------------- launcher ----------------
extern "C" void kernel_launch(void* const* d_in, const int* in_sizes, int n_in,
                              void* d_out, int out_size, void* d_ws, size_t ws_size,
                              hipStream_t stream)
{
  const float* x   = (const float*)d_in[0];
  const float* c1w = (const float*)d_in[1];
  const float* c1b = (const float*)d_in[2];
  const float* g1  = (const float*)d_in[3];
  const float* be1 = (const float*)d_in[4];
  const float* c2w = (const float*)d_in[5];
  const float* c2b = (const float*)d_in[6];
  const float* g2  = (const float*)d_in[7];
  const float* be2 = (const float*)d_in[8];
  const float* aw  = (const float*)d_in[9];
  const float* ab  = (const float*)d_in[10];
  const float* wih = (const float*)d_in[11];
  const float* whh = (const float*)d_in[12];
  const float* bih = (const float*)d_in[13];
  const float* bhh = (const float*)d_in[14];
  const float* l1w = (const float*)d_in[15];
  const float* l1b = (const float*)d_in[16];
  const float* l2w = (const float*)d_in[17];
  const float* l2b = (const float*)d_in[18];
  const float* muw = (const float*)d_in[19];
  const float* mub = (const float*)d_in[20];
  const float* sgw = (const float*)d_in[21];
  const float* sgb = (const float*)d_in[22];

  float* ws    = (float*)d_ws;
  float* stat1 = ws;                    // 12
  float* stat2 = ws + 12;               // 12
  float* aff1  = ws + 24;               // 12
  float* aff2  = ws + 36;               // 12
  int*   prog  = (int*)(ws + 64);       // 192 used
  int*   cons  = (int*)(ws + 304);      // 192 used
  float* y1    = ws + 576;              // 64*6*1020
  float* y2    = y1 + 391680;           // 64*6*1016
  float* seq0  = y2 + 390144;           // 1016*768
  float* ring  = seq0 + 780288;         // 192 hops * 8 batches * 192 floats
  float* hfin  = ring + (size_t)192 * RB * 192;   // 120*768

  hipMemsetAsync(d_ws, 0, 576 * sizeof(float), stream);  // zero stats + flags

  k_conv<<<384, 256, 0, stream>>>(x, c1w, c1b, nullptr, y1, stat1, 1024, 1020, 0);
  k_finalize<<<1, 64, 0, stream>>>(stat1, g1, be1, aff1, 1.f / 65280.f);
  k_conv<<<384, 256, 0, stream>>>(y1, c2w, c2b, aff1, y2, stat2, 1020, 1016, 1);
  k_finalize<<<1, 64, 0, stream>>>(stat2, g2, be2, aff2, 1.f / 65024.f);
  k_attn<<<1016, 768, 0, stream>>>(y2, aff2, aw, ab, seq0);
  k_lstm<<<128, TPB, 0, stream>>>(wih, whh, bih, bhh, seq0, ring, prog, cons, hfin);
  k_head<<<30, 256, 0, stream>>>(hfin, l1w, l1b, l2w, l2b, muw, mub, sgw, sgb, (float*)d_out);
}

// Round 10
// 857.736 us; speedup vs baseline: 3.1836x; 1.5859x over previous
//
#include <hip/hip_runtime.h>
#include <math.h>

// ---------------- problem constants ----------------
#define NLAY 120         // LSTM layers
#define TT   1016        // LSTM time steps (1024 - 4 - 4)
#define NB   64          // batches of 16 steps
#define RB   8           // L3 ring depth in batches (power of 2)
#define IRS  32          // inter-wave LDS ring slots (power of 2)
#define TPB  384         // 6 waves x 64 lanes; wave = 5 layers x 12 hidden (lanes 60-63 pad)
#define BIGF (1 << 20)

typedef float v2f __attribute__((ext_vector_type(2)));
typedef __fp16 h2 __attribute__((ext_vector_type(2)));   // matches cvt_pkrtz/fdot2 builtin type

__device__ __forceinline__ float fast_rcp(float x) { return __builtin_amdgcn_rcpf(x); }
__device__ __forceinline__ float fast_sig(float x) { return fast_rcp(1.f + __expf(-x)); }
__device__ __forceinline__ float fast_tanh(float x) { return 1.f - 2.f * fast_rcp(1.f + __expf(2.f * x)); }

__device__ __forceinline__ int poll_ge_ag(const int* p, int tgt, int cur) {
  long g = 0;
  while (cur < tgt) {
    cur = __hip_atomic_load(p, __ATOMIC_RELAXED, __HIP_MEMORY_SCOPE_AGENT);
    if (cur >= tgt) break;
    __builtin_amdgcn_s_sleep(1);
    if (++g > 400000L) break;   // fail loud, never hang
  }
  return cur;
}
__device__ __forceinline__ int poll_ge_wg(const int* p, int tgt, int cur) {
  long g = 0;
  while (cur < tgt) {
    cur = __hip_atomic_load(p, __ATOMIC_RELAXED, __HIP_MEMORY_SCOPE_WORKGROUP);
    if (cur >= tgt) break;
    __builtin_amdgcn_s_sleep(1);
    if (++g > 400000L) break;
  }
  return cur;
}

// ---------------- conv1d(6->6,K=5,valid) + bias, accumulate BN stats ----------------
__global__ void k_conv(const float* __restrict__ xin, const float* __restrict__ cw,
                       const float* __restrict__ cb, const float* __restrict__ aff,
                       float* __restrict__ yout, float* __restrict__ stat,
                       int Tin, int Tout, int use_aff)
{
  const int bx = blockIdx.x;
  const int b = bx / 6, co = bx - b * 6;
  const int tid = threadIdx.x;
  __shared__ float wsh[30];
  __shared__ float ssh[6], shsh[6];
  if (tid < 30) wsh[tid] = cw[co * 30 + tid];
  if (tid < 6) {
    ssh[tid]  = use_aff ? aff[tid] : 1.f;
    shsh[tid] = use_aff ? aff[6 + tid] : 0.f;
  }
  __syncthreads();
  const float bias = cb[co];
  float lsum = 0.f, lsq = 0.f;
  for (int t = tid; t < Tout; t += 256) {
    float acc = bias;
#pragma unroll
    for (int ci = 0; ci < 6; ++ci) {
      const float* xr = xin + ((size_t)b * 6 + ci) * Tin + t;
      const float s = ssh[ci], sh = shsh[ci];
#pragma unroll
      for (int k = 0; k < 5; ++k) {
        float v = xr[k];
        if (use_aff) v = fmaxf(fmaf(s, v, sh), 0.f);
        acc += wsh[ci * 5 + k] * v;
      }
    }
    yout[((size_t)b * 6 + co) * Tout + t] = acc;
    lsum += acc; lsq += acc * acc;
  }
  __shared__ float rs[256], rq[256];
  rs[tid] = lsum; rq[tid] = lsq;
  __syncthreads();
  for (int s = 128; s > 0; s >>= 1) {
    if (tid < s) { rs[tid] += rs[tid + s]; rq[tid] += rq[tid + s]; }
    __syncthreads();
  }
  if (tid == 0) { atomicAdd(&stat[co], rs[0]); atomicAdd(&stat[6 + co], rq[0]); }
}

__global__ void k_finalize(const float* __restrict__ stat,
                           const float* __restrict__ gamma, const float* __restrict__ beta,
                           float* __restrict__ aff, float invN)
{
  const int c = threadIdx.x;
  if (c < 6) {
    float mean = stat[c] * invN;
    float var  = stat[6 + c] * invN - mean * mean;
    float sc   = gamma[c] * rsqrtf(var + 1e-5f);
    aff[c]     = sc;
    aff[6 + c] = fmaf(-mean, sc, beta[c]);
  }
}

__global__ void k_attn(const float* __restrict__ y2, const float* __restrict__ aff2,
                       const float* __restrict__ aw, const float* __restrict__ ab,
                       float* __restrict__ seq0)
{
  const int t = blockIdx.x;
  const int tid = threadIdx.x;
  __shared__ float zb[6 * 64];
  if (tid < 384) {
    const int c = tid >> 6, bb = tid & 63;
    float v = y2[((size_t)bb * 6 + c) * TT + t];
    zb[c * 64 + bb] = fmaxf(fmaf(aff2[c], v, aff2[6 + c]), 0.f);
  }
  __syncthreads();
  const int b = tid / 12, j = tid - b * 12;
  float acc = ab[j];
#pragma unroll
  for (int c = 0; c < 6; ++c) acc += aw[j * 6 + c] * zb[c * 64 + b];
  seq0[(size_t)t * 768 + tid] = fmaxf(acc, 0.f);
}

// ---------------- 120-layer LSTM: R5 structure + f16 dot2 datapath ----------------
// 256 blocks = chain*4 + seg. Wave w = 5-layer stage; lane (p,j) = layer w*5+p, unit j.
// Diagonal: group p computes t = s - p. h exchanged as PACKED F16 pairs in per-wave LDS
// (v_dot2_f32_f16: 2 MACs/slot, fp32 accumulate); biases/c-state/L3 rings stay fp32.
// Wave->wave: fp32 iring + relaxed LDS flags cadence 4. Block->block: 16-step L3 batches.
__global__ __launch_bounds__(TPB, 2) void k_lstm(
    const float* __restrict__ wih, const float* __restrict__ whh,
    const float* __restrict__ bih, const float* __restrict__ bhh,
    const float* __restrict__ seq0, float* __restrict__ ring,
    int* __restrict__ prog, int* __restrict__ cons,
    float* __restrict__ hfin)
{
  const int bid  = blockIdx.x;         // 0..255
  const int c    = bid >> 2;           // chain = batch element
  const int seg  = bid & 3;
  const int tid  = threadIdx.x;
  const int w    = tid >> 6;           // wave 0..5
  const int lane = tid & 63;
  const int p    = lane / 12;          // 0..5 (5 = pad)
  const int j    = lane - p * 12;
  const bool act = (p < 5);
  const int pc   = act ? p : 0;
  const int l    = seg * 30 + w * 5 + pc;

  // ---- LDS ----
  __shared__ __align__(16) __fp16 hlocH[6][2][96];      // per-wave f16 h (5 layers x 16-pad + pad grp)
  __shared__ __align__(16) float iring[5][IRS][12];     // wave w -> w+1 (fp32)
  __shared__ __align__(16) float xring[2][16][12];      // feeder input (fp32)
  __shared__ __align__(16) float oring[16][12];         // tailer staging (fp32)
  __shared__ int pflag[8], cflag[8];
  float* xrf = &xring[0][0][0];

  if (tid < 8) { pflag[tid] = 0; cflag[tid] = 0; }
  {
    __fp16 z = (__fp16)0.f;
    hlocH[w][0][lane] = z; hlocH[w][1][lane] = z;
    hlocH[w][0][64 + (lane & 31)] = z; hlocH[w][1][64 + (lane & 31)] = z;
  }
  __syncthreads();   // ONE barrier, before the main loop only

  // ---- gate weights packed to f16 K-pairs: w[gate][kk] = (w[row][2kk], w[row][2kk+1]) ----
  h2 wx[4][6] = {}, wh2v[4][6] = {};
  float bias[4] = {0.f, 0.f, 0.f, 0.f};
  if (act) {
    const float* wi = wih + l * 576;
    const float* wh = whh + l * 576;
#pragma unroll
    for (int q = 0; q < 4; ++q) {
      const int row = j + 12 * q;   // torch gate order i,f,g,o
#pragma unroll
      for (int kk = 0; kk < 6; ++kk) {
        wx[q][kk]   = __builtin_amdgcn_cvt_pkrtz(wi[row * 12 + 2 * kk], wi[row * 12 + 2 * kk + 1]);
        wh2v[q][kk] = __builtin_amdgcn_cvt_pkrtz(wh[row * 12 + 2 * kk], wh[row * 12 + 2 * kk + 1]);
      }
      bias[q] = bih[l * 48 + row] + bhh[l * 48 + row];
    }
  }

  // ---- feeder / tailer plumbing (unchanged from R5) ----
  const int hop_in  = c * 3 + seg - 1;
  const int hop_out = c * 3 + seg;
  const bool has_up = (seg > 0), has_dn = (seg < 3);
  const float* rin  = ring + (size_t)(has_up ? hop_in : 0) * (RB * 192);
  float*       rout = ring + (size_t)(has_dn ? hop_out : 0) * (RB * 192);
  const bool is_feeder = (w == 0);
  const bool is_tailer = (w == 5) && has_dn;

  const int f0 = lane, f1 = lane + 64, f2 = lane + 128;
  const int s0o0 = (f0 / 12) * 768 + (f0 % 12);
  const int s0o1 = (f1 / 12) * 768 + (f1 % 12);
  const int s0o2 = (f2 / 12) * 768 + (f2 % 12);

  auto ld_batch = [&](int m, float* d) {
    if (seg == 0) {
      const float* b = seq0 + (size_t)m * 16 * 768 + c * 12;
      d[0] = b[s0o0]; d[1] = b[s0o1]; d[2] = b[s0o2];
    } else {
      const float* b = rin + (m & (RB - 1)) * 192;
      d[0] = __hip_atomic_load(b + f0, __ATOMIC_RELAXED, __HIP_MEMORY_SCOPE_AGENT);
      d[1] = __hip_atomic_load(b + f1, __ATOMIC_RELAXED, __HIP_MEMORY_SCOPE_AGENT);
      d[2] = __hip_atomic_load(b + f2, __ATOMIC_RELAXED, __HIP_MEMORY_SCOPE_AGENT);
    }
  };

  float pend[3] = {0.f, 0.f, 0.f};
  int kp = 0, kcons = 0;
  if (is_feeder) {
    if (has_up) kp = poll_ge_ag(&prog[hop_in], 2, 0);
    float cur[3];
    ld_batch(0, cur);
    ld_batch(1, pend);
    xrf[f0] = cur[0]; xrf[f1] = cur[1]; xrf[f2] = cur[2];
  }

  float cst = 0.f, hn = 0.f;
  int pcache = 0, ccache = 0;

  auto step = [&](int s, bool guard) __attribute__((always_inline)) {
    const int rb = (s & 1) ^ 1, wb = s & 1;

    // ---- inputs: packed f16 pairs ----
    h2 px[6], ph[6];
    {
      const h2* hp = (const h2*)&hlocH[w][rb][pc * 16];
#pragma unroll
      for (int kk = 0; kk < 6; ++kk) ph[kk] = hp[kk];
    }
    if (p == 0) {   // x from fp32 ring -> convert to f16 pairs
      const float4* xp = (w == 0)
          ? (const float4*)(xrf + ((s >> 4) & 1) * 192 + (s & 15) * 12)
          : (const float4*)(&iring[w - 1][s & (IRS - 1)][0]);
      float4 a = xp[0], b4 = xp[1], d = xp[2];
      px[0] = __builtin_amdgcn_cvt_pkrtz(a.x, a.y);
      px[1] = __builtin_amdgcn_cvt_pkrtz(a.z, a.w);
      px[2] = __builtin_amdgcn_cvt_pkrtz(b4.x, b4.y);
      px[3] = __builtin_amdgcn_cvt_pkrtz(b4.z, b4.w);
      px[4] = __builtin_amdgcn_cvt_pkrtz(d.x, d.y);
      px[5] = __builtin_amdgcn_cvt_pkrtz(d.z, d.w);
    } else {
      const h2* xp = (const h2*)&hlocH[w][rb][(pc - (pc > 0)) * 16];
#pragma unroll
      for (int kk = 0; kk < 6; ++kk) px[kk] = xp[kk];
    }

    // ---- 4 gates: 12 fdot2 each (fp32 accumulate from bias) ----
    float a0 = bias[0], a1 = bias[1], a2 = bias[2], a3 = bias[3];
#pragma unroll
    for (int kk = 0; kk < 6; ++kk) {
      a0 = __builtin_amdgcn_fdot2(wx[0][kk], px[kk], a0, false);
      a1 = __builtin_amdgcn_fdot2(wx[1][kk], px[kk], a1, false);
      a2 = __builtin_amdgcn_fdot2(wx[2][kk], px[kk], a2, false);
      a3 = __builtin_amdgcn_fdot2(wx[3][kk], px[kk], a3, false);
    }
#pragma unroll
    for (int kk = 0; kk < 6; ++kk) {
      a0 = __builtin_amdgcn_fdot2(wh2v[0][kk], ph[kk], a0, false);
      a1 = __builtin_amdgcn_fdot2(wh2v[1][kk], ph[kk], a1, false);
      a2 = __builtin_amdgcn_fdot2(wh2v[2][kk], ph[kk], a2, false);
      a3 = __builtin_amdgcn_fdot2(wh2v[3][kk], ph[kk], a3, false);
    }
    float ig = fast_sig(a0);
    float fg = fast_sig(a1);
    float gv = fast_tanh(a2);
    float og = fast_sig(a3);

    if (!guard) {
      cst = fg * cst + ig * gv;
      hn  = og * fast_tanh(cst);
      hlocH[w][wb][p * 16 + j] = (__fp16)hn;   // pad group writes slots 80..95 harmlessly
      if (p == 4) {
        const int t = s - 4;
        if (w < 5) iring[w][t & (IRS - 1)][j] = hn;
        else if (has_dn) oring[t & 15][j] = hn;
      }
    } else {
      const int t = s - pc;
      const bool run = act && (t >= 0) && (t < TT);
      if (run) {
        cst = fg * cst + ig * gv;
        hn  = og * fast_tanh(cst);
      }
      hlocH[w][wb][p * 16 + j] = (__fp16)hn;
      if (p == 4 && t >= 0 && t < TT) {
        if (w < 5) iring[w][t & (IRS - 1)][j] = hn;
        else if (has_dn) oring[t & 15][j] = hn;
      }
      if (run && t == TT - 1) hfin[l * 768 + c * 12 + j] = hn;
    }

    if (is_tailer) {
      const int t4 = s - 4;
      if (t4 >= 0 && t4 < TT && (((t4 & 15) == 15) || t4 == TT - 1)) {
        const int m4 = t4 >> 4;
        if (kcons < m4 - (RB - 1) + 1)
          kcons = poll_ge_ag(&cons[hop_out], m4 - RB + 1, kcons);
        const float* orf = &oring[0][0];
        float o0 = orf[f0], o1 = orf[f1], o2 = orf[f2];
        float* d = rout + (m4 & (RB - 1)) * 192;
        __hip_atomic_store(d + f0, o0, __ATOMIC_RELAXED, __HIP_MEMORY_SCOPE_AGENT);
        __hip_atomic_store(d + f1, o1, __ATOMIC_RELAXED, __HIP_MEMORY_SCOPE_AGENT);
        __hip_atomic_store(d + f2, o2, __ATOMIC_RELAXED, __HIP_MEMORY_SCOPE_AGENT);
        if (lane == 0)
          __hip_atomic_store(&prog[hop_out], m4 + 1, __ATOMIC_RELEASE, __HIP_MEMORY_SCOPE_AGENT);
      }
    }
  };

  for (int s4 = 0; s4 < 1024; s4 += 4) {
    if (is_feeder && (s4 & 15) == 0) {
      const int m = s4 >> 4;
      if (m + 1 < NB) {
        float* xd = xrf + ((m + 1) & 1) * 192;
        xd[f0] = pend[0]; xd[f1] = pend[1]; xd[f2] = pend[2];
      }
      if (m + 2 < NB) {
        if (has_up && kp < m + 3) kp = poll_ge_ag(&prog[hop_in], m + 3, kp);
        ld_batch(m + 2, pend);
      }
      if (has_up && lane == 0)
        __hip_atomic_store(&cons[hop_in], m, __ATOMIC_RELAXED, __HIP_MEMORY_SCOPE_AGENT);
    }

    if (w > 0 && s4 < TT) {
      const int tgt = (s4 + 4 < TT) ? (s4 + 4) : TT;
      if (pcache < tgt) {
        pcache = poll_ge_wg(&pflag[w - 1], tgt, pcache);
        asm volatile("" ::: "memory");
      }
    }
    if (w < 5 && s4 >= 36) {
      const int tgt = s4 - 32;
      if (ccache < tgt) {
        ccache = poll_ge_wg(&cflag[w + 1], tgt, ccache);
        asm volatile("" ::: "memory");
      }
    }

    if (s4 >= 4 && s4 < 1012) {
      step(s4 + 0, false); step(s4 + 1, false); step(s4 + 2, false); step(s4 + 3, false);
    } else {
      step(s4 + 0, true);  step(s4 + 1, true);  step(s4 + 2, true);  step(s4 + 3, true);
    }

    if (lane == 0) {
      asm volatile("" ::: "memory");
      if (w < 5)
        __hip_atomic_store(&pflag[w], s4, __ATOMIC_RELAXED, __HIP_MEMORY_SCOPE_WORKGROUP);
      if (w > 0 && s4 + 3 < TT)
        __hip_atomic_store(&cflag[w], s4 + 4, __ATOMIC_RELAXED, __HIP_MEMORY_SCOPE_WORKGROUP);
    }
  }

  if (lane == 0) {
    asm volatile("" ::: "memory");
    if (w < 5) __hip_atomic_store(&pflag[w], BIGF, __ATOMIC_RELAXED, __HIP_MEMORY_SCOPE_WORKGROUP);
    if (w > 0) __hip_atomic_store(&cflag[w], BIGF, __ATOMIC_RELAXED, __HIP_MEMORY_SCOPE_WORKGROUP);
    if (is_feeder && has_up)
      __hip_atomic_store(&cons[hop_in], BIGF, __ATOMIC_RELAXED, __HIP_MEMORY_SCOPE_AGENT);
  }
}

// ---------------- head: lin1+relu, lin2+relu, mu, softplus(sigma) ----------------
__global__ void k_head(const float* __restrict__ hfin,
                       const float* __restrict__ w1, const float* __restrict__ b1,
                       const float* __restrict__ w2, const float* __restrict__ b2,
                       const float* __restrict__ wm, const float* __restrict__ bm,
                       const float* __restrict__ wsg, const float* __restrict__ bsg,
                       float* __restrict__ out)
{
  const int tid = threadIdx.x;
  __shared__ float s1[144], s2[144], sm[144], ss[144];
  __shared__ float v1[12], v2[12], vm[12], vs[12];
  if (tid < 144) { s1[tid] = w1[tid]; s2[tid] = w2[tid]; sm[tid] = wm[tid]; ss[tid] = wsg[tid]; }
  if (tid < 12)  { v1[tid] = b1[tid]; v2[tid] = b2[tid]; vm[tid] = bm[tid]; vs[tid] = bsg[tid]; }
  __syncthreads();
  const int r = blockIdx.x * 256 + tid;
  const int b = r / 120, l = r - b * 120;
  float h[12];
#pragma unroll
  for (int k = 0; k < 12; ++k) h[k] = hfin[l * 768 + b * 12 + k];
  float u1[12];
#pragma unroll
  for (int u = 0; u < 12; ++u) {
    float a = v1[u];
#pragma unroll
    for (int k = 0; k < 12; ++k) a += s1[u * 12 + k] * h[k];
    u1[u] = fmaxf(a, 0.f);
  }
  float u2[12];
#pragma unroll
  for (int u = 0; u < 12; ++u) {
    float a = v2[u];
#pragma unroll
    for (int k = 0; k < 12; ++k) a += s2[u * 12 + k] * u1[k];
    u2[u] = fmaxf(a, 0.f);
  }
  const size_t base = (size_t)r * 12;
#pragma unroll
  for (int u = 0; u < 12; ++u) out[base + u] = u2[u];
#pragma unroll
  for (int u = 0; u < 12; ++u) {
    float a = vm[u];
#pragma unroll
    for (int k = 0; k < 12; ++k) a += sm[u * 12 + k] * u2[k];
    out[92160 + base + u] = a;
  }
#pragma unroll
  for (int u = 0; u < 12; ++u) {
    float a = vs[u];
#pragma unroll
    for (int k = 0; k < 12; ++k) a += ss[u * 12 + k] * u2[k];
    out[184320 + base + u] = fmaxf(a, 0.f) + log1pf(expf(-fabsf(a)));
  }
}

// ---------------- launcher ----------------
extern "C" void kernel_launch(void* const* d_in, const int* in_sizes, int n_in,
                              void* d_out, int out_size, void* d_ws, size_t ws_size,
                              hipStream_t stream)
{
  const float* x   = (const float*)d_in[0];
  const float* c1w = (const float*)d_in[1];
  const float* c1b = (const float*)d_in[2];
  const float* g1  = (const float*)d_in[3];
  const float* be1 = (const float*)d_in[4];
  const float* c2w = (const float*)d_in[5];
  const float* c2b = (const float*)d_in[6];
  const float* g2  = (const float*)d_in[7];
  const float* be2 = (const float*)d_in[8];
  const float* aw  = (const float*)d_in[9];
  const float* ab  = (const float*)d_in[10];
  const float* wih = (const float*)d_in[11];
  const float* whh = (const float*)d_in[12];
  const float* bih = (const float*)d_in[13];
  const float* bhh = (const float*)d_in[14];
  const float* l1w = (const float*)d_in[15];
  const float* l1b = (const float*)d_in[16];
  const float* l2w = (const float*)d_in[17];
  const float* l2b = (const float*)d_in[18];
  const float* muw = (const float*)d_in[19];
  const float* mub = (const float*)d_in[20];
  const float* sgw = (const float*)d_in[21];
  const float* sgb = (const float*)d_in[22];

  float* ws    = (float*)d_ws;
  float* stat1 = ws;                    // 12
  float* stat2 = ws + 12;               // 12
  float* aff1  = ws + 24;               // 12
  float* aff2  = ws + 36;               // 12
  int*   prog  = (int*)(ws + 64);       // 192 used
  int*   cons  = (int*)(ws + 304);      // 192 used
  float* y1    = ws + 576;              // 64*6*1020
  float* y2    = y1 + 391680;           // 64*6*1016
  float* seq0  = y2 + 390144;           // 1016*768
  float* ring  = seq0 + 780288;         // 192 hops * 8 batches * 192 floats
  float* hfin  = ring + (size_t)192 * RB * 192;   // 120*768

  (void)hipMemsetAsync(d_ws, 0, 576 * sizeof(float), stream);  // zero stats + flags

  k_conv<<<384, 256, 0, stream>>>(x, c1w, c1b, nullptr, y1, stat1, 1024, 1020, 0);
  k_finalize<<<1, 64, 0, stream>>>(stat1, g1, be1, aff1, 1.f / 65280.f);
  k_conv<<<384, 256, 0, stream>>>(y1, c2w, c2b, aff1, y2, stat2, 1020, 1016, 1);
  k_finalize<<<1, 64, 0, stream>>>(stat2, g2, be2, aff2, 1.f / 65024.f);
  k_attn<<<1016, 768, 0, stream>>>(y2, aff2, aw, ab, seq0);
  k_lstm<<<256, TPB, 0, stream>>>(wih, whh, bih, bhh, seq0, ring, prog, cons, hfin);
  k_head<<<30, 256, 0, stream>>>(hfin, l1w, l1b, l2w, l2b, muw, mub, sgw, sgb, (float*)d_out);
}